// Round 1
// baseline (1417.832 us; speedup 1.0000x reference)
//
#include <hip/hip_runtime.h>
#include <math.h>

#define HW 96
#define N_VOX (96*96*96)        // 884736 voxels per volume
#define NVOL 8                  // 4 pred + 4 target volumes
#define NEL (4*N_VOX)           // 3538944 elements in pred/target
#define PLANE (96*96)           // 9216

// ---------------------------------------------------------------------------
// foreground test: v in [0,4) -> pred volume v (sigmoid(x)>0.5),
//                  v in [4,8) -> target volume v-4 (t>0.5)
__device__ __forceinline__ bool fg_at(const float* __restrict__ pred,
                                      const float* __restrict__ targ,
                                      int v, int j) {
    if (v < 4) {
        float x = pred[(size_t)v * N_VOX + j];
        float p = 1.0f / (1.0f + expf(-x));
        return p > 0.5f;
    } else {
        return targ[(size_t)(v - 4) * N_VOX + j] > 0.5f;
    }
}

// ---------------------------------------------------------------------------
// focal loss partial sum
__global__ void focal_kernel(const float* __restrict__ x,
                             const float* __restrict__ t,
                             float* __restrict__ acc, int n) {
    int idx = blockIdx.x * blockDim.x + threadIdx.x;
    int stride = gridDim.x * blockDim.x;
    float sum = 0.0f;
    for (int i = idx; i < n; i += stride) {
        float xv = x[i];
        float tv = t[i];
        float p  = 1.0f / (1.0f + expf(-xv));
        float pt = (tv == 1.0f) ? p : 1.0f - p;
        // stable softplus: max(x,0) + log1p(exp(-|x|))
        float sp  = fmaxf(xv, 0.0f) + log1pf(expf(-fabsf(xv)));
        float bce = sp - xv * tv;
        float at  = (tv == 1.0f) ? 0.25f : 0.75f;
        float om  = 1.0f - pt;
        sum += at * om * om * bce;
    }
    __shared__ float sdata[256];
    sdata[threadIdx.x] = sum;
    __syncthreads();
    for (int s = blockDim.x >> 1; s > 0; s >>= 1) {
        if (threadIdx.x < s) sdata[threadIdx.x] += sdata[threadIdx.x + s];
        __syncthreads();
    }
    if (threadIdx.x == 0) atomicAdd(acc, sdata[0]);
}

// ---------------------------------------------------------------------------
// CCL: init labels to local voxel index
__global__ void ccl_init(int* __restrict__ L) {
    int j = blockIdx.x * blockDim.x + threadIdx.x;
    if (j >= N_VOX) return;
    L[(size_t)blockIdx.y * N_VOX + j] = j;
}

// lock-free union-find merge (Playne-Hawick). Labels only decrease; all
// linking decisions via device-scope atomicMin, so stale cached reads only
// cause retries, never incorrect unions.
__device__ __forceinline__ void merge_labels(int* __restrict__ L, int l1, int l2) {
    while (l1 != l2 && l1 != L[l1]) l1 = L[l1];
    while (l1 != l2 && l2 != L[l2]) l2 = L[l2];
    while (l1 != l2) {
        if (l1 < l2) { int tmp = l1; l1 = l2; l2 = tmp; }  // l1 > l2
        int l3 = atomicMin(&L[l1], l2);
        l1 = (l3 == l1) ? l2 : l3;
    }
}

// one pass over forward edges (+d, +w, +h) per foreground voxel
__global__ void ccl_merge(const float* __restrict__ pred,
                          const float* __restrict__ targ,
                          int* __restrict__ L, int vbase) {
    int j = blockIdx.x * blockDim.x + threadIdx.x;
    if (j >= N_VOX) return;
    int vloc = blockIdx.y;
    int v = vbase + vloc;
    if (!fg_at(pred, targ, v, j)) return;
    int* Lv = L + (size_t)vloc * N_VOX;

    int d = j % 96;
    int r = j / 96;
    int w = r % 96;
    int h = r / 96;

    if (d < 95 && fg_at(pred, targ, v, j + 1))     merge_labels(Lv, j, j + 1);
    if (w < 95 && fg_at(pred, targ, v, j + 96))    merge_labels(Lv, j, j + 96);
    if (h < 95 && fg_at(pred, targ, v, j + PLANE)) merge_labels(Lv, j, j + PLANE);
}

// count roots (L[j]==j on foreground) per volume
__global__ void ccl_count(const float* __restrict__ pred,
                          const float* __restrict__ targ,
                          const int* __restrict__ L,
                          int* __restrict__ counts, int vbase) {
    int j = blockIdx.x * blockDim.x + threadIdx.x;
    if (j >= N_VOX) return;
    int vloc = blockIdx.y;
    int v = vbase + vloc;
    if (!fg_at(pred, targ, v, j)) return;
    if (L[(size_t)vloc * N_VOX + j] == j) atomicAdd(&counts[v], 1);
}

// ---------------------------------------------------------------------------
// combine: out = focal_mean + 0.1 * mean_c | mean_b cc_p - mean_b cc_t |
__global__ void finalize_kernel(const float* __restrict__ acc,
                                const int* __restrict__ counts,
                                float* __restrict__ out) {
    float focal = acc[0] / (float)NEL;
    // pred vols: b*C+c -> {0:(0,0),1:(0,1),2:(1,0),3:(1,1)}; targ vols +4
    float dp0 = 0.5f * (float)(counts[0] + counts[2]);  // class 0 pred mean
    float dp1 = 0.5f * (float)(counts[1] + counts[3]);  // class 1 pred mean
    float dt0 = 0.5f * (float)(counts[4] + counts[6]);
    float dt1 = 0.5f * (float)(counts[5] + counts[7]);
    float topo = 0.5f * (fabsf(dp0 - dt0) + fabsf(dp1 - dt1));
    out[0] = focal + 0.1f * topo;
}

// ---------------------------------------------------------------------------
extern "C" void kernel_launch(void* const* d_in, const int* in_sizes, int n_in,
                              void* d_out, int out_size, void* d_ws, size_t ws_size,
                              hipStream_t stream) {
    const float* pred = (const float*)d_in[0];
    const float* targ = (const float*)d_in[1];
    float* out = (float*)d_out;

    // workspace layout: [0..3] float focal acc; [64..95] int counts[8];
    // [256..) labels
    float* acc    = (float*)d_ws;
    int*   counts = (int*)((char*)d_ws + 64);
    int*   labels = (int*)((char*)d_ws + 256);

    size_t avail_ints = (ws_size > 256) ? (ws_size - 256) / 4 : 0;
    int vols_per_pass = (int)(avail_ints / N_VOX);
    if (vols_per_pass > NVOL) vols_per_pass = NVOL;
    if (vols_per_pass < 1) vols_per_pass = 1;  // assume ws >= ~3.6MB

    hipMemsetAsync(d_ws, 0, 256, stream);

    focal_kernel<<<1024, 256, 0, stream>>>(pred, targ, acc, NEL);

    dim3 blk(256);
    int blocks_x = (N_VOX + 255) / 256;
    for (int vbase = 0; vbase < NVOL; vbase += vols_per_pass) {
        int nv = NVOL - vbase;
        if (nv > vols_per_pass) nv = vols_per_pass;
        dim3 grid(blocks_x, nv);
        ccl_init <<<grid, blk, 0, stream>>>(labels);
        ccl_merge<<<grid, blk, 0, stream>>>(pred, targ, labels, vbase);
        ccl_count<<<grid, blk, 0, stream>>>(pred, targ, labels, counts, vbase);
    }

    finalize_kernel<<<1, 1, 0, stream>>>(acc, counts, out);
}

// Round 2
// 876.568 us; speedup vs baseline: 1.6175x; 1.6175x over previous
//
#include <hip/hip_runtime.h>
#include <math.h>

#define HW 96
#define N_VOX (96*96*96)        // 884736 voxels per volume
#define NVOL 8                  // 4 pred + 4 target volumes
#define NEL (4*N_VOX)           // 3538944 elements in pred/target
#define PLANE (96*96)           // 9216

// tile geometry for local CCL: full d-span x TW x TH
#define TW 8
#define TH 8
#define TILES_W (96/TW)         // 12
#define TILES_H (96/TH)         // 12
#define TILE_VOX (96*TW*TH)     // 6144
#define ROWS_PER_TILE (TW*TH)   // 64 rows of 96

// ---------------------------------------------------------------------------
// foreground test: v in [0,4) -> pred volume v (sigmoid(x)>0.5 == x>0),
//                  v in [4,8) -> target volume v-4 (t>0.5)
__device__ __forceinline__ bool fg_at(const float* __restrict__ pred,
                                      const float* __restrict__ targ,
                                      int v, int j) {
    if (v < 4) {
        float x = pred[(size_t)v * N_VOX + j];
        float p = 1.0f / (1.0f + expf(-x));
        return p > 0.5f;
    } else {
        return targ[(size_t)(v - 4) * N_VOX + j] > 0.5f;
    }
}

// ---------------------------------------------------------------------------
// focal loss partial sum
__global__ void focal_kernel(const float* __restrict__ x,
                             const float* __restrict__ t,
                             float* __restrict__ acc, int n) {
    int idx = blockIdx.x * blockDim.x + threadIdx.x;
    int stride = gridDim.x * blockDim.x;
    float sum = 0.0f;
    for (int i = idx; i < n; i += stride) {
        float xv = x[i];
        float tv = t[i];
        float p  = 1.0f / (1.0f + expf(-xv));
        float pt = (tv == 1.0f) ? p : 1.0f - p;
        float sp  = fmaxf(xv, 0.0f) + log1pf(expf(-fabsf(xv)));
        float bce = sp - xv * tv;
        float at  = (tv == 1.0f) ? 0.25f : 0.75f;
        float om  = 1.0f - pt;
        sum += at * om * om * bce;
    }
    __shared__ float sdata[256];
    sdata[threadIdx.x] = sum;
    __syncthreads();
    for (int s = blockDim.x >> 1; s > 0; s >>= 1) {
        if (threadIdx.x < s) sdata[threadIdx.x] += sdata[threadIdx.x + s];
        __syncthreads();
    }
    if (threadIdx.x == 0) atomicAdd(acc, sdata[0]);
}

// ---------------------------------------------------------------------------
// lock-free union-find merge on GLOBAL labels (Playne-Hawick). Labels only
// decrease; all linking via device-scope atomicMin -> stale plain reads only
// cause retries, never bad unions.
__device__ __forceinline__ void merge_labels(int* __restrict__ L, int l1, int l2) {
    while (l1 != l2 && l1 != L[l1]) l1 = L[l1];
    while (l1 != l2 && l2 != L[l2]) l2 = L[l2];
    while (l1 != l2) {
        if (l1 < l2) { int tmp = l1; l1 = l2; l2 = tmp; }  // l1 > l2
        int l3 = atomicMin(&L[l1], l2);
        l1 = (l3 == l1) ? l2 : l3;
    }
}

// same on LDS labels
__device__ __forceinline__ void merge_local(int* lab, int l1, int l2) {
    while (l1 != l2 && l1 != lab[l1]) l1 = lab[l1];
    while (l1 != l2 && l2 != lab[l2]) l2 = lab[l2];
    while (l1 != l2) {
        if (l1 < l2) { int tmp = l1; l1 = l2; l2 = tmp; }
        int l3 = atomicMin(&lab[l1], l2);
        l1 = (l3 == l1) ? l2 : l3;
    }
}

// ---------------------------------------------------------------------------
// Phase 1: per-tile CCL in LDS; write resolved tile-roots (global indices)
// to Lg for every fg voxel. bg labels are left unwritten (never read later).
__global__ __launch_bounds__(256) void ccl_local(const float* __restrict__ pred,
                                                 const float* __restrict__ targ,
                                                 int* __restrict__ Lg, int vbase) {
    __shared__ int lab[TILE_VOX];
    __shared__ unsigned char fgs[TILE_VOX];
    int vloc = blockIdx.y;
    int v = vbase + vloc;
    int tile = blockIdx.x;                 // 0..143
    int w0 = (tile % TILES_W) * TW;
    int h0 = (tile / TILES_W) * TH;
    int* Lvg = Lg + (size_t)vloc * N_VOX;

    // load fg + init local labels
    for (int i = threadIdx.x; i < TILE_VOX; i += blockDim.x) {
        int d = i % 96, lw = (i / 96) % TW, lh = i / (96 * TW);
        int j = (h0 + lh) * PLANE + (w0 + lw) * 96 + d;
        bool f = fg_at(pred, targ, v, j);
        fgs[i] = f ? 1 : 0;
        lab[i] = i;
    }
    __syncthreads();

    // intra-tile merges (3 forward edges per fg voxel), LDS atomics only
    for (int i = threadIdx.x; i < TILE_VOX; i += blockDim.x) {
        if (!fgs[i]) continue;
        int d = i % 96, lw = (i / 96) % TW, lh = i / (96 * TW);
        if (d  < 95     && fgs[i + 1])       merge_local(lab, i, i + 1);
        if (lw < TW - 1 && fgs[i + 96])      merge_local(lab, i, i + 96);
        if (lh < TH - 1 && fgs[i + 96*TW])   merge_local(lab, i, i + 96*TW);
    }
    __syncthreads();

    // resolve to local root, convert to global index, store
    for (int i = threadIdx.x; i < TILE_VOX; i += blockDim.x) {
        if (!fgs[i]) continue;
        int r = i;
        while (lab[r] != r) r = lab[r];
        int d  = i % 96, lw = (i / 96) % TW, lh = i / (96 * TW);
        int j  = (h0 + lh) * PLANE + (w0 + lw) * 96 + d;
        int rd = r % 96, rw = (r / 96) % TW, rh = r / (96 * TW);
        int gr = (h0 + rh) * PLANE + (w0 + rw) * 96 + rd;
        Lvg[j] = gr;  // local->global map is order-preserving: gr <= j
    }
}

// ---------------------------------------------------------------------------
// Phase 2: merge tile-boundary edges only (backward -w and -h faces)
__global__ void ccl_boundary(const float* __restrict__ pred,
                             const float* __restrict__ targ,
                             int* __restrict__ Lg, int vbase) {
    int j = blockIdx.x * blockDim.x + threadIdx.x;
    if (j >= N_VOX) return;
    int w = (j / 96) % 96;
    int h = j / PLANE;
    bool wb = (w % TW == 0) && (w > 0);
    bool hb = (h % TH == 0) && (h > 0);
    if (!wb && !hb) return;
    int vloc = blockIdx.y;
    int v = vbase + vloc;
    if (!fg_at(pred, targ, v, j)) return;
    int* Lv = Lg + (size_t)vloc * N_VOX;
    if (wb && fg_at(pred, targ, v, j - 96))    merge_labels(Lv, j, j - 96);
    if (hb && fg_at(pred, targ, v, j - PLANE)) merge_labels(Lv, j, j - PLANE);
}

// ---------------------------------------------------------------------------
// count roots (L[j]==j on foreground) per volume
__global__ void ccl_count(const float* __restrict__ pred,
                          const float* __restrict__ targ,
                          const int* __restrict__ L,
                          int* __restrict__ counts, int vbase) {
    int j = blockIdx.x * blockDim.x + threadIdx.x;
    if (j >= N_VOX) return;
    int vloc = blockIdx.y;
    int v = vbase + vloc;
    if (!fg_at(pred, targ, v, j)) return;
    if (L[(size_t)vloc * N_VOX + j] == j) atomicAdd(&counts[v], 1);
}

// ---------------------------------------------------------------------------
__global__ void finalize_kernel(const float* __restrict__ acc,
                                const int* __restrict__ counts,
                                float* __restrict__ out) {
    float focal = acc[0] / (float)NEL;
    float dp0 = 0.5f * (float)(counts[0] + counts[2]);
    float dp1 = 0.5f * (float)(counts[1] + counts[3]);
    float dt0 = 0.5f * (float)(counts[4] + counts[6]);
    float dt1 = 0.5f * (float)(counts[5] + counts[7]);
    float topo = 0.5f * (fabsf(dp0 - dt0) + fabsf(dp1 - dt1));
    out[0] = focal + 0.1f * topo;
}

// ---------------------------------------------------------------------------
extern "C" void kernel_launch(void* const* d_in, const int* in_sizes, int n_in,
                              void* d_out, int out_size, void* d_ws, size_t ws_size,
                              hipStream_t stream) {
    const float* pred = (const float*)d_in[0];
    const float* targ = (const float*)d_in[1];
    float* out = (float*)d_out;

    float* acc    = (float*)d_ws;
    int*   counts = (int*)((char*)d_ws + 64);
    int*   labels = (int*)((char*)d_ws + 256);

    size_t avail_ints = (ws_size > 256) ? (ws_size - 256) / 4 : 0;
    int vols_per_pass = (int)(avail_ints / N_VOX);
    if (vols_per_pass > NVOL) vols_per_pass = NVOL;
    if (vols_per_pass < 1) vols_per_pass = 1;

    hipMemsetAsync(d_ws, 0, 256, stream);

    focal_kernel<<<1024, 256, 0, stream>>>(pred, targ, acc, NEL);

    dim3 blk(256);
    int blocks_x = (N_VOX + 255) / 256;
    for (int vbase = 0; vbase < NVOL; vbase += vols_per_pass) {
        int nv = NVOL - vbase;
        if (nv > vols_per_pass) nv = vols_per_pass;
        dim3 tgrid(TILES_W * TILES_H, nv);
        ccl_local   <<<tgrid, blk, 0, stream>>>(pred, targ, labels, vbase);
        dim3 grid(blocks_x, nv);
        ccl_boundary<<<grid, blk, 0, stream>>>(pred, targ, labels, vbase);
        ccl_count   <<<grid, blk, 0, stream>>>(pred, targ, labels, counts, vbase);
    }

    finalize_kernel<<<1, 1, 0, stream>>>(acc, counts, out);
}

// Round 3
// 359.414 us; speedup vs baseline: 3.9448x; 2.4389x over previous
//
#include <hip/hip_runtime.h>
#include <math.h>

#define HW 96
#define N_VOX (96*96*96)        // 884736 voxels per volume
#define NVOL 8                  // 4 pred + 4 target volumes
#define NEL (4*N_VOX)           // 3538944 elements in pred/target
#define PLANE (96*96)           // 9216

// tile geometry for local CCL: full d-span x TW x TH
#define TW 8
#define TH 8
#define TILES_W (96/TW)         // 12
#define TILES_H (96/TH)         // 12
#define TILE_VOX (96*TW*TH)     // 6144

// boundary faces: w in {8,..,88} (11 planes) and h likewise
#define NBPLANES 11
#define FACE_VOX (NBPLANES*PLANE)       // 101376
#define BOUND_VOX (2*FACE_VOX)          // 202752

// ---------------------------------------------------------------------------
__device__ __forceinline__ bool fg_at(const float* __restrict__ pred,
                                      const float* __restrict__ targ,
                                      int v, int j) {
    if (v < 4) {
        float x = pred[(size_t)v * N_VOX + j];
        float p = 1.0f / (1.0f + expf(-x));
        return p > 0.5f;
    } else {
        return targ[(size_t)(v - 4) * N_VOX + j] > 0.5f;
    }
}

// ---------------------------------------------------------------------------
// focal loss partial sum
__global__ void focal_kernel(const float* __restrict__ x,
                             const float* __restrict__ t,
                             float* __restrict__ acc, int n) {
    int idx = blockIdx.x * blockDim.x + threadIdx.x;
    int stride = gridDim.x * blockDim.x;
    float sum = 0.0f;
    for (int i = idx; i < n; i += stride) {
        float xv = x[i];
        float tv = t[i];
        float p  = 1.0f / (1.0f + expf(-xv));
        float pt = (tv == 1.0f) ? p : 1.0f - p;
        float sp  = fmaxf(xv, 0.0f) + log1pf(expf(-fabsf(xv)));
        float bce = sp - xv * tv;
        float at  = (tv == 1.0f) ? 0.25f : 0.75f;
        float om  = 1.0f - pt;
        sum += at * om * om * bce;
    }
    __shared__ float sdata[256];
    sdata[threadIdx.x] = sum;
    __syncthreads();
    for (int s = blockDim.x >> 1; s > 0; s >>= 1) {
        if (threadIdx.x < s) sdata[threadIdx.x] += sdata[threadIdx.x + s];
        __syncthreads();
    }
    if (threadIdx.x == 0) atomicAdd(acc, sdata[0]);
}

// ---------------------------------------------------------------------------
// lock-free union-find merge on GLOBAL labels (Playne-Hawick).
__device__ __forceinline__ void merge_labels(int* __restrict__ L, int l1, int l2) {
    while (l1 != l2 && l1 != L[l1]) l1 = L[l1];
    while (l1 != l2 && l2 != L[l2]) l2 = L[l2];
    while (l1 != l2) {
        if (l1 < l2) { int tmp = l1; l1 = l2; l2 = tmp; }  // l1 > l2
        int l3 = atomicMin(&L[l1], l2);
        l1 = (l3 == l1) ? l2 : l3;
    }
}

// same on LDS labels
__device__ __forceinline__ void merge_local(int* lab, int l1, int l2) {
    while (l1 != l2 && l1 != lab[l1]) l1 = lab[l1];
    while (l1 != l2 && l2 != lab[l2]) l2 = lab[l2];
    while (l1 != l2) {
        if (l1 < l2) { int tmp = l1; l1 = l2; l2 = tmp; }
        int l3 = atomicMin(&lab[l1], l2);
        l1 = (l3 == l1) ? l2 : l3;
    }
}

// ---------------------------------------------------------------------------
// Phase 1: per-tile CCL in LDS; write resolved tile-roots (global indices)
// for fg voxels, -1 for bg voxels (so later phases never touch pred/targ).
__global__ __launch_bounds__(256) void ccl_local(const float* __restrict__ pred,
                                                 const float* __restrict__ targ,
                                                 int* __restrict__ Lg, int vbase) {
    __shared__ int lab[TILE_VOX];
    __shared__ unsigned char fgs[TILE_VOX];
    int vloc = blockIdx.y;
    int v = vbase + vloc;
    int tile = blockIdx.x;                 // 0..143
    int w0 = (tile % TILES_W) * TW;
    int h0 = (tile / TILES_W) * TH;
    int* Lvg = Lg + (size_t)vloc * N_VOX;

    for (int i = threadIdx.x; i < TILE_VOX; i += blockDim.x) {
        int d = i % 96, lw = (i / 96) % TW, lh = i / (96 * TW);
        int j = (h0 + lh) * PLANE + (w0 + lw) * 96 + d;
        bool f = fg_at(pred, targ, v, j);
        fgs[i] = f ? 1 : 0;
        lab[i] = i;
    }
    __syncthreads();

    for (int i = threadIdx.x; i < TILE_VOX; i += blockDim.x) {
        if (!fgs[i]) continue;
        int d = i % 96, lw = (i / 96) % TW, lh = i / (96 * TW);
        if (d  < 95     && fgs[i + 1])       merge_local(lab, i, i + 1);
        if (lw < TW - 1 && fgs[i + 96])      merge_local(lab, i, i + 96);
        if (lh < TH - 1 && fgs[i + 96*TW])   merge_local(lab, i, i + 96*TW);
    }
    __syncthreads();

    for (int i = threadIdx.x; i < TILE_VOX; i += blockDim.x) {
        int d  = i % 96, lw = (i / 96) % TW, lh = i / (96 * TW);
        int j  = (h0 + lh) * PLANE + (w0 + lw) * 96 + d;
        int val = -1;
        if (fgs[i]) {
            int r = i;
            while (lab[r] != r) r = lab[r];
            int rd = r % 96, rw = (r / 96) % TW, rh = r / (96 * TW);
            val = (h0 + rh) * PLANE + (w0 + rw) * 96 + rd;  // <= j, order-preserving
        }
        Lvg[j] = val;
    }
}

// ---------------------------------------------------------------------------
// Phase 2: merge tile-boundary edges only, using labels for the fg test
// (L[j] >= 0 iff foreground). Compact launch: 2*11 planes per volume.
__global__ void ccl_boundary(int* __restrict__ Lg, int nv) {
    int tid = blockIdx.x * blockDim.x + threadIdx.x;
    if (tid >= BOUND_VOX) return;
    int vloc = blockIdx.y;
    int* Lv = Lg + (size_t)vloc * N_VOX;

    int j, jn;
    if (tid < FACE_VOX) {               // w-faces: w in {8,16,...,88}
        int p   = tid / PLANE;          // 0..10
        int rem = tid % PLANE;
        int h = rem / 96, d = rem % 96;
        int w = (p + 1) * TW;
        j  = h * PLANE + w * 96 + d;
        jn = j - 96;
    } else {                            // h-faces: h in {8,16,...,88}
        int t2  = tid - FACE_VOX;
        int p   = t2 / PLANE;
        int rem = t2 % PLANE;
        int w = rem / 96, d = rem % 96;
        int h = (p + 1) * TH;
        j  = h * PLANE + w * 96 + d;
        jn = j - PLANE;
    }
    if (Lv[j] >= 0 && Lv[jn] >= 0) merge_labels(Lv, j, jn);
}

// ---------------------------------------------------------------------------
// Phase 3: count roots (L[j]==j) per volume; int4 loads + block reduction.
__global__ __launch_bounds__(256) void ccl_count(const int* __restrict__ L,
                                                 int* __restrict__ counts, int vbase) {
    int vloc = blockIdx.y;
    const int4* Lv = (const int4*)(L + (size_t)vloc * N_VOX);
    int t = blockIdx.x * blockDim.x + threadIdx.x;   // int4 index
    int cnt = 0;
    if (t < N_VOX / 4) {
        int4 q = Lv[t];
        int b = t * 4;
        cnt = (q.x == b) + (q.y == b + 1) + (q.z == b + 2) + (q.w == b + 3);
    }
    __shared__ int s[256];
    s[threadIdx.x] = cnt;
    __syncthreads();
    for (int st = 128; st > 0; st >>= 1) {
        if (threadIdx.x < st) s[threadIdx.x] += s[threadIdx.x + st];
        __syncthreads();
    }
    if (threadIdx.x == 0 && s[0]) atomicAdd(&counts[vbase + vloc], s[0]);
}

// ---------------------------------------------------------------------------
__global__ void finalize_kernel(const float* __restrict__ acc,
                                const int* __restrict__ counts,
                                float* __restrict__ out) {
    float focal = acc[0] / (float)NEL;
    float dp0 = 0.5f * (float)(counts[0] + counts[2]);
    float dp1 = 0.5f * (float)(counts[1] + counts[3]);
    float dt0 = 0.5f * (float)(counts[4] + counts[6]);
    float dt1 = 0.5f * (float)(counts[5] + counts[7]);
    float topo = 0.5f * (fabsf(dp0 - dt0) + fabsf(dp1 - dt1));
    out[0] = focal + 0.1f * topo;
}

// ---------------------------------------------------------------------------
extern "C" void kernel_launch(void* const* d_in, const int* in_sizes, int n_in,
                              void* d_out, int out_size, void* d_ws, size_t ws_size,
                              hipStream_t stream) {
    const float* pred = (const float*)d_in[0];
    const float* targ = (const float*)d_in[1];
    float* out = (float*)d_out;

    float* acc    = (float*)d_ws;
    int*   counts = (int*)((char*)d_ws + 64);
    int*   labels = (int*)((char*)d_ws + 256);

    size_t avail_ints = (ws_size > 256) ? (ws_size - 256) / 4 : 0;
    int vols_per_pass = (int)(avail_ints / N_VOX);
    if (vols_per_pass > NVOL) vols_per_pass = NVOL;
    if (vols_per_pass < 1) vols_per_pass = 1;

    hipMemsetAsync(d_ws, 0, 256, stream);

    focal_kernel<<<1024, 256, 0, stream>>>(pred, targ, acc, NEL);

    for (int vbase = 0; vbase < NVOL; vbase += vols_per_pass) {
        int nv = NVOL - vbase;
        if (nv > vols_per_pass) nv = vols_per_pass;
        dim3 tgrid(TILES_W * TILES_H, nv);
        ccl_local<<<tgrid, dim3(256), 0, stream>>>(pred, targ, labels, vbase);
        dim3 bgrid((BOUND_VOX + 255) / 256, nv);
        ccl_boundary<<<bgrid, dim3(256), 0, stream>>>(labels, nv);
        dim3 cgrid((N_VOX / 4 + 255) / 256, nv);
        ccl_count<<<cgrid, dim3(256), 0, stream>>>(labels, counts, vbase);
    }

    finalize_kernel<<<1, 1, 0, stream>>>(acc, counts, out);
}